// Round 4
// baseline (243.112 us; speedup 1.0000x reference)
//
#include <hip/hip_runtime.h>
#include <hip/hip_bf16.h>
#include <stdint.h>

#define KFULL 1120
#define N4H   2048
#define MTOT  131072   // B*T

typedef float f32x4 __attribute__((ext_vector_type(4)));
typedef __bf16 bf16x8 __attribute__((ext_vector_type(8)));
typedef unsigned short u16;
typedef unsigned short ush8 __attribute__((ext_vector_type(8)));

__device__ __forceinline__ u16 f2bf(float f){
  union { float f; unsigned u; } v; v.f = f;
  unsigned u = v.u;
  u += 0x7fffu + ((u >> 16) & 1u);   // RNE
  return (u16)(u >> 16);
}
__device__ __forceinline__ float sigf(float x){ return 1.f / (1.f + __expf(-x)); }
__device__ __forceinline__ float tanh_fast(float x){ return 1.f - 2.f / (__expf(2.f * x) + 1.f); }
// chunk swizzle for 64B LDS rows read as 16B chunks (verified rounds 1-3)
__device__ __forceinline__ int swz(int row){ return (row ^ (row >> 2)) & 3; }

// ---------------- prep: pre-transposed, pre-swizzled bf16 B matrices ----------------
__global__ void prep_w(const float* __restrict__ Wi, const float* __restrict__ Wh,
                       const float* __restrict__ Km, const float* __restrict__ R,
                       u16* __restrict__ wiT, u16* __restrict__ whT, u16* __restrict__ wfT){
  int idx = blockIdx.x * 256 + threadIdx.x;
  if (idx < 524288){                       // Wi and Wh: 16*512*32 each
    const float* src = (idx < 262144) ? Wi : Wh;
    u16* dst = (idx < 262144) ? wiT : whT;
    int e = idx & 262143;
    int n = e & 511, kk = (e >> 9) & 31, s = e >> 14;
    float v = src[(size_t)(s * 32 + kk) * 512 + n];
    int dkk = (kk & 7) | ((((kk >> 3) ^ swz(n)) & 3) << 3);
    dst[((size_t)s * 512 + n) * 32 + dkk] = f2bf(v);
  } else {
    int e = idx - 524288;                  // Wfull = [K(608); R(512)] x 2048
    if (e >= 35 * 2048 * 32) return;
    int n = e & 2047, kk = (e >> 11) & 31, s = e >> 16;
    int k = s * 32 + kk;
    float v = (k < 608) ? Km[(size_t)k * 2048 + n] : R[(size_t)(k - 608) * 2048 + n];
    int dkk = (kk & 7) | ((((kk >> 3) ^ swz(n)) & 3) << 3);
    wfT[((size_t)s * 2048 + n) * 32 + dkk] = f2bf(v);
  }
}

// x_full[:, 512:1120] = [onehots | prev_h]
__global__ void prep_x(const float* __restrict__ onehots, const float* __restrict__ prev_h,
                       float* __restrict__ x_full){
  int idx = blockIdx.x * 256 + threadIdx.x;
  if (idx >= 512 * 608) return;
  int b = idx / 608, c = idx % 608;
  float v = (c < 96) ? onehots[b * 96 + c] : prev_h[b * 512 + (c - 96)];
  x_full[(size_t)b * KFULL + 512 + c] = v;
}

// ---------------- 128x128-tile bf16 GEMM, 256 threads, 4 waves (2x2) ----------------
// Counted-vmcnt pipeline (T4): B gl_lds double-buffered depth-1, A fp32 prefetched
// depth-2 into 2 register sets. Barrier = vmcnt(4)+lgkmcnt(0)+s_barrier: forces
// B(s+1) landed, keeps A(s+2)'s 4 loads in flight ACROSS the barrier.
template<int EPI, int KSTEPS>
__launch_bounds__(256, 3)
__global__ void gemm128(const float* __restrict__ A, int lda,
                        const u16* __restrict__ Bt, int ntot,
                        float* __restrict__ outp, size_t partStride,
                        const float* __restrict__ hpart, const float* __restrict__ bh,
                        const float* __restrict__ Ws, float* __restrict__ epart){
  __shared__ u16 smA[2][128 * 32];    // 2 x 8KB, swizzled 64B rows
  __shared__ u16 smB[2][128 * 32];    // 2 x 8KB, swizzle baked in global layout
  __shared__ float smHp[128];
  __shared__ float smWs[128];
  __shared__ float smRed[2][128];

  const int tid  = threadIdx.x;
  const int lane = tid & 63, w = tid >> 6;
  const int wr = w >> 1, wc = w & 1;
  const int fr = lane & 15, g = lane >> 4;

  int m0, n0, s0;
  if (EPI == 1){
    // bijective XCD swizzle: 4096 wgs, 512/XCD; same-m0 n-blocks land on one XCD
    int bid = blockIdx.x;
    int sw = (bid & 7) * 512 + (bid >> 3);
    m0 = (sw >> 2) * 128;
    n0 = (sw & 3) * 128;
    s0 = 0;
  } else {
    m0 = blockIdx.x * 128;
    n0 = blockIdx.y * 128;
    s0 = blockIdx.z * KSTEPS;
    outp += (size_t)blockIdx.z * partStride;
  }

  if (EPI == 1 && tid < 128){
    int b = m0 >> 8;
    float h = bh[n0 + tid];
    #pragma unroll
    for (int p = 0; p < 4; ++p) h += hpart[(size_t)p * 262144 + (size_t)b * 512 + n0 + tid];
    smHp[tid] = h;
    smWs[tid] = Ws[n0 + tid];
  }

  f32x4 acc[4][4] = {};

  // A staging map: thread -> rows (ar, ar+64), 8 cols at ac
  const int ar = tid >> 2;
  const int ac = (tid & 3) * 8;
  const float* ap = A + (size_t)(m0 + ar) * lda + ac;
  const int sz  = swz(ar);                       // swz(ar+64) == swz(ar)
  const int ab0 = ar * 64 + (((tid & 3) ^ sz) << 4);
  const int ab1 = ab0 + 64 * 64;

  // two A prefetch register sets (depth-2)
  float4 pa0[4], pa1[4];

#define ISSUE_B(sabs, c) do {                                              \
    const char* bsrc = (const char*)Bt + ((size_t)(sabs) * ntot + n0) * 64;\
    _Pragma("unroll")                                                      \
    for (int j = 0; j < 2; ++j){                                           \
      int off = w * 2048 + j * 1024;                                       \
      __builtin_amdgcn_global_load_lds(                                    \
        (const __attribute__((address_space(1))) void*)(bsrc + off + lane * 16), \
        (__attribute__((address_space(3))) void*)((char*)&smB[c][0] + off),\
        16, 0, 0);                                                         \
    }                                                                      \
  } while(0)

#define LOAD_A(s, R) do {                                                  \
    int kc = (s0 + (s)) * 32;                                              \
    R[0] = *(const float4*)(ap + kc);                                      \
    R[1] = *(const float4*)(ap + kc + 4);                                  \
    R[2] = *(const float4*)(ap + (size_t)64 * lda + kc);                   \
    R[3] = *(const float4*)(ap + (size_t)64 * lda + kc + 4);               \
  } while(0)

#define WRITE_A(R, c) do {                                                 \
    ush8 w0, w1;                                                           \
    w0[0]=f2bf(R[0].x); w0[1]=f2bf(R[0].y); w0[2]=f2bf(R[0].z); w0[3]=f2bf(R[0].w);\
    w0[4]=f2bf(R[1].x); w0[5]=f2bf(R[1].y); w0[6]=f2bf(R[1].z); w0[7]=f2bf(R[1].w);\
    w1[0]=f2bf(R[2].x); w1[1]=f2bf(R[2].y); w1[2]=f2bf(R[2].z); w1[3]=f2bf(R[2].w);\
    w1[4]=f2bf(R[3].x); w1[5]=f2bf(R[3].y); w1[6]=f2bf(R[3].z); w1[7]=f2bf(R[3].w);\
    *(ush8*)((char*)&smA[c][0] + ab0) = w0;                                \
    *(ush8*)((char*)&smA[c][0] + ab1) = w1;                                \
  } while(0)

#define COMPUTE(c) do {                                                    \
    bf16x8 af[4];                                                          \
    _Pragma("unroll")                                                      \
    for (int m = 0; m < 4; ++m){                                           \
      int rl = wr * 64 + m * 16 + fr;                                      \
      af[m] = *(const bf16x8*)((const char*)&smA[c][0] + rl * 64 + ((g ^ swz(rl)) << 4)); \
    }                                                                      \
    _Pragma("unroll")                                                      \
    for (int n = 0; n < 4; ++n){                                           \
      int nl = wc * 64 + n * 16 + fr;                                      \
      bf16x8 bfv = *(const bf16x8*)((const char*)&smB[c][0] + nl * 64 + ((g ^ swz(nl)) << 4)); \
      _Pragma("unroll")                                                    \
      for (int m = 0; m < 4; ++m)                                          \
        acc[m][n] = __builtin_amdgcn_mfma_f32_16x16x32_bf16(af[m], bfv, acc[m][n], 0, 0, 0); \
    }                                                                      \
  } while(0)

  // ---- prologue: B(0) -> buf0; A(0) -> pa0; A(1) -> pa1; stage A(0) into LDS ----
  ISSUE_B(s0, 0);
  LOAD_A(0, pa0);
  if (KSTEPS > 1) LOAD_A(1, pa1);
  WRITE_A(pa0, 0);      // compiler's own vmcnt wait: A(1)'s 4 loads stay outstanding
  asm volatile("s_waitcnt vmcnt(4)" ::: "memory");   // force B(0)+A(0) landed
  asm volatile("s_waitcnt lgkmcnt(0)" ::: "memory");
  __builtin_amdgcn_s_barrier();

  // ---- main loop, fully unrolled (KSTEPS compile-time) ----
  #pragma unroll
  for (int s = 0; s < KSTEPS; ++s){
    if (s + 1 < KSTEPS) ISSUE_B(s0 + s + 1, (s + 1) & 1);   // 2 gl_lds
    if (s + 2 < KSTEPS){                                    // 4 global loads
      if ((s & 1) == 0) LOAD_A(s + 2, pa0);
      else              LOAD_A(s + 2, pa1);
    }
    COMPUTE(s & 1);                                         // 8 ds_read + 16 MFMA
    if (s + 1 < KSTEPS){
      if (((s + 1) & 1) == 0) WRITE_A(pa0, 0);              // f2bf + 2 ds_write
      else                    WRITE_A(pa1, 1);
      // counted barrier: force B(s+1) gl_lds done; A(s+2) stays in flight
      if (s + 2 < KSTEPS) asm volatile("s_waitcnt vmcnt(4)" ::: "memory");
      else                asm volatile("s_waitcnt vmcnt(0)" ::: "memory");
      asm volatile("s_waitcnt lgkmcnt(0)" ::: "memory");
      __builtin_amdgcn_s_barrier();
    }
  }

#undef ISSUE_B
#undef LOAD_A
#undef WRITE_A
#undef COMPUTE

  if (EPI == 0){
    #pragma unroll
    for (int n = 0; n < 4; ++n){
      int col = n0 + wc * 64 + n * 16 + fr;
      #pragma unroll
      for (int m = 0; m < 4; ++m){
        int row = m0 + wr * 64 + m * 16 + g * 4;
        #pragma unroll
        for (int j = 0; j < 4; ++j)
          outp[(size_t)(row + j) * ntot + col] = acc[m][n][j];
      }
    }
  } else {
    float p[16] = {};
    #pragma unroll
    for (int n = 0; n < 4; ++n){
      int col = wc * 64 + n * 16 + fr;
      float hpv = smHp[col], wsv = smWs[col];
      #pragma unroll
      for (int m = 0; m < 4; ++m)
        #pragma unroll
        for (int j = 0; j < 4; ++j)
          p[m * 4 + j] += tanh_fast(acc[m][n][j] + hpv) * wsv;
    }
    #pragma unroll
    for (int mask = 1; mask < 16; mask <<= 1)
      #pragma unroll
      for (int i = 0; i < 16; ++i)
        p[i] += __shfl_xor(p[i], mask);
    if (fr == 0){
      #pragma unroll
      for (int m = 0; m < 4; ++m)
        #pragma unroll
        for (int j = 0; j < 4; ++j)
          smRed[wc][wr * 64 + m * 16 + g * 4 + j] = p[m * 4 + j];
    }
    __syncthreads();
    if (tid < 128){
      int nb = n0 >> 7;
      epart[(size_t)nb * MTOT + m0 + tid] = smRed[0][tid] + smRed[1][tid];
    }
  }
}

// ---------------- fused softmax + context: x_full[:,0:512], alpha -> d_out ----------------
__global__ void ctx_softmax(const float* __restrict__ epart, const float* __restrict__ batch_H,
                            float* __restrict__ x_full, float* __restrict__ alpha_out){
  __shared__ float sa[256];
  __shared__ float red[4], red2[4];
  __shared__ f32x4 sred[8][32];
  int b = blockIdx.x, q = blockIdx.y, tid = threadIdx.x;

  float e = 0.f;
  #pragma unroll
  for (int p = 0; p < 4; ++p) e += epart[(size_t)p * MTOT + b * 256 + tid];
  float m = e;
  #pragma unroll
  for (int mask = 1; mask < 64; mask <<= 1) m = fmaxf(m, __shfl_xor(m, mask));
  int w = tid >> 6;
  if ((tid & 63) == 0) red[w] = m;
  __syncthreads();
  m = fmaxf(fmaxf(red[0], red[1]), fmaxf(red[2], red[3]));
  float ev = __expf(e - m);
  float s = ev;
  #pragma unroll
  for (int mask = 1; mask < 64; mask <<= 1) s += __shfl_xor(s, mask);
  if ((tid & 63) == 0) red2[w] = s;
  __syncthreads();
  s = red2[0] + red2[1] + red2[2] + red2[3];
  float a = ev / s;
  sa[tid] = a;
  if (q == 0) alpha_out[(size_t)b * 256 + tid] = a;
  __syncthreads();

  int c4 = tid & 31, tq = tid >> 5;
  const float4* bhp = (const float4*)(batch_H + (size_t)b * 131072) + (size_t)tq * 32 * 128 + q * 32 + c4;
  f32x4 acc = {0.f, 0.f, 0.f, 0.f};
  #pragma unroll 4
  for (int t = 0; t < 32; ++t){
    float av = sa[tq * 32 + t];
    float4 v = bhp[(size_t)t * 128];
    acc[0] += av * v.x; acc[1] += av * v.y; acc[2] += av * v.z; acc[3] += av * v.w;
  }
  sred[tq][c4] = acc;
  __syncthreads();
  if (tid < 32){
    f32x4 o = sred[0][tid];
    #pragma unroll
    for (int r = 1; r < 8; ++r){
      f32x4 v = sred[r][tid];
      o[0] += v[0]; o[1] += v[1]; o[2] += v[2]; o[3] += v[3];
    }
    float4 st; st.x = o[0]; st.y = o[1]; st.z = o[2]; st.w = o[3];
    *(float4*)(x_full + (size_t)b * KFULL + q * 128 + tid * 4) = st;
  }
}

// ---------------- LSTM gates: sum z parts + bias, apply gates ----------------
__global__ void gates_k(const float* __restrict__ zpart, const float* __restrict__ bias,
                        const float* __restrict__ prev_c, float* __restrict__ out){
  int idx = blockIdx.x * 256 + threadIdx.x;   // 512*512
  int b = idx >> 9, h = idx & 511;
  float zi = bias[h], zf = bias[512 + h], zg = bias[1024 + h], zo = bias[1536 + h];
  #pragma unroll
  for (int p = 0; p < 5; ++p){
    const float* zr = zpart + (size_t)p * 1048576 + (size_t)b * N4H;
    zi += zr[h]; zf += zr[512 + h]; zg += zr[1024 + h]; zo += zr[1536 + h];
  }
  float c = sigf(zf) * prev_c[idx] + sigf(zi) * tanh_fast(zg);
  float hn = sigf(zo) * tanh_fast(c);
  out[idx] = hn;               // h_new
  out[262144 + idx] = c;       // c_new
}

extern "C" void kernel_launch(void* const* d_in, const int* in_sizes, int n_in,
                              void* d_out, int out_size, void* d_ws, size_t ws_size,
                              hipStream_t stream){
  const float* prev_h  = (const float*)d_in[0];
  const float* prev_c  = (const float*)d_in[1];
  const float* batch_H = (const float*)d_in[2];
  const float* onehots = (const float*)d_in[3];
  const float* Wi      = (const float*)d_in[4];
  const float* Wh      = (const float*)d_in[5];
  const float* bh      = (const float*)d_in[6];
  const float* Ws      = (const float*)d_in[7];
  const float* Km      = (const float*)d_in[8];
  const float* R       = (const float*)d_in[9];
  const float* bb      = (const float*)d_in[10];
  float* out = (float*)d_out;

  char* ws = (char*)d_ws;
  u16*  wiT    = (u16*)(ws + 0);             // 512KB
  u16*  whT    = (u16*)(ws + 524288);        // 512KB
  u16*  wfT    = (u16*)(ws + 1048576);       // 4.375MB -> 5636096
  float* hpart = (float*)(ws + 5636096);     // 4MB -> 9830400
  float* epart = (float*)(ws + 9830400);     // 2MB -> 11927552
  float* x_full= (float*)(ws + 11927552);    // 2.1875MB -> 14221312
  float* zpart = (float*)(ws + 14221312);    // 20MB -> 35192832

  float* alpha = out + 524288;

  prep_w<<<11008, 256, 0, stream>>>(Wi, Wh, Km, R, wiT, whT, wfT);
  prep_x<<<1216, 256, 0, stream>>>(onehots, prev_h, x_full);
  gemm128<0, 4><<<dim3(4, 4, 4), 256, 0, stream>>>(prev_h, 512, whT, 512,
                                                   hpart, 262144, nullptr, nullptr, nullptr, nullptr);
  gemm128<1, 16><<<dim3(4096, 1, 1), 256, 0, stream>>>(batch_H, 512, wiT, 512,
                                                       nullptr, 0, hpart, bh, Ws, epart);
  ctx_softmax<<<dim3(512, 4), 256, 0, stream>>>(epart, batch_H, x_full, alpha);
  gemm128<0, 7><<<dim3(4, 16, 5), 256, 0, stream>>>(x_full, KFULL, wfT, N4H,
                                                    zpart, 1048576, nullptr, nullptr, nullptr, nullptr);
  gates_k<<<1024, 256, 0, stream>>>(zpart, bb, prev_c, out);
}

// Round 5
// 205.482 us; speedup vs baseline: 1.1831x; 1.1831x over previous
//
#include <hip/hip_runtime.h>
#include <hip/hip_bf16.h>
#include <stdint.h>

#define KFULL 1120
#define N4H   2048
#define MTOT  131072   // B*T

typedef float f32x4 __attribute__((ext_vector_type(4)));
typedef __bf16 bf16x8 __attribute__((ext_vector_type(8)));
typedef unsigned short u16;

__device__ __forceinline__ u16 f2bf_bits(float f){
  __bf16 b = (__bf16)f;                  // RNE, lowers to v_cvt_pk_bf16_f32
  union { __bf16 b; u16 u; } cv; cv.b = b;
  return cv.u;
}
__device__ __forceinline__ float sigf(float x){ return 1.f / (1.f + __expf(-x)); }
__device__ __forceinline__ float tanh_fast(float x){ return 1.f - 2.f / (__expf(2.f * x) + 1.f); }
// chunk swizzle for 64B LDS rows read as 16B chunks (verified rounds 1-4)
__device__ __forceinline__ int swz(int row){ return (row ^ (row >> 2)) & 3; }

// ---------------- prep: pre-transposed, pre-swizzled bf16 B matrices ----------------
__global__ void prep_w(const float* __restrict__ Wi, const float* __restrict__ Wh,
                       const float* __restrict__ Km, const float* __restrict__ R,
                       u16* __restrict__ wiT, u16* __restrict__ whT, u16* __restrict__ wfT){
  int idx = blockIdx.x * 256 + threadIdx.x;
  if (idx < 524288){                       // Wi and Wh: 16*512*32 each
    const float* src = (idx < 262144) ? Wi : Wh;
    u16* dst = (idx < 262144) ? wiT : whT;
    int e = idx & 262143;
    int n = e & 511, kk = (e >> 9) & 31, s = e >> 14;
    float v = src[(size_t)(s * 32 + kk) * 512 + n];
    int dkk = (kk & 7) | ((((kk >> 3) ^ swz(n)) & 3) << 3);
    dst[((size_t)s * 512 + n) * 32 + dkk] = f2bf_bits(v);
  } else {
    int e = idx - 524288;                  // Wfull = [K(608); R(512)] x 2048
    if (e >= 35 * 2048 * 32) return;
    int n = e & 2047, kk = (e >> 11) & 31, s = e >> 16;
    int k = s * 32 + kk;
    float v = (k < 608) ? Km[(size_t)k * 2048 + n] : R[(size_t)(k - 608) * 2048 + n];
    int dkk = (kk & 7) | ((((kk >> 3) ^ swz(n)) & 3) << 3);
    wfT[((size_t)s * 2048 + n) * 32 + dkk] = f2bf_bits(v);
  }
}

// x_full[:, 512:1120] = [onehots | prev_h]
__global__ void prep_x(const float* __restrict__ onehots, const float* __restrict__ prev_h,
                       float* __restrict__ x_full){
  int idx = blockIdx.x * 256 + threadIdx.x;
  if (idx >= 512 * 608) return;
  int b = idx / 608, c = idx % 608;
  float v = (c < 96) ? onehots[b * 96 + c] : prev_h[b * 512 + (c - 96)];
  x_full[(size_t)b * KFULL + 512 + c] = v;
}

// ---------------- 128x128-tile bf16 GEMM, 256 threads, 4 waves (2x2) ----------------
// R2 structure (best measured): stage -> sync -> compute -> sync.
// Only change vs R2: fp32->bf16 conversion via native casts (v_cvt_pk_bf16_f32),
// killing the ~90-VALU-op hand-RNE chain per thread per K-step.
template<int EPI>
__launch_bounds__(256, 3)
__global__ void gemm128(const float* __restrict__ A, int lda, int ksteps,
                        const u16* __restrict__ Bt, int ntot,
                        float* __restrict__ outp, size_t partStride,
                        const float* __restrict__ hpart, const float* __restrict__ bh,
                        const float* __restrict__ Ws, float* __restrict__ epart){
  __shared__ u16 smA[128 * 32];    // 8KB, swizzled 64B rows
  __shared__ u16 smB[128 * 32];    // 8KB, swizzle baked in global layout
  __shared__ float smHp[128];
  __shared__ float smWs[128];
  __shared__ float smRed[2][128];

  const int tid  = threadIdx.x;
  const int lane = tid & 63, w = tid >> 6;
  const int wr = w >> 1, wc = w & 1;
  const int fr = lane & 15, g = lane >> 4;

  int m0, n0, s0;
  if (EPI == 1){
    // bijective XCD swizzle: 4096 wgs, 512/XCD; same-m0 n-blocks land on one XCD
    int bid = blockIdx.x;
    int sw = (bid & 7) * 512 + (bid >> 3);
    m0 = (sw >> 2) * 128;
    n0 = (sw & 3) * 128;
    s0 = 0;
  } else {
    m0 = blockIdx.x * 128;
    n0 = blockIdx.y * 128;
    s0 = blockIdx.z * ksteps;
    outp += (size_t)blockIdx.z * partStride;
  }

  if (EPI == 1 && tid < 128){
    int b = m0 >> 8;
    float h = bh[n0 + tid];
    #pragma unroll
    for (int p = 0; p < 4; ++p) h += hpart[(size_t)p * 262144 + (size_t)b * 512 + n0 + tid];
    smHp[tid] = h;
    smWs[tid] = Ws[n0 + tid];
  }

  f32x4 acc[4][4] = {};

  // A staging map: thread -> rows (ar, ar+64), 8 cols at ac
  const int ar = tid >> 2;
  const int ac = (tid & 3) * 8;
  const float* ap = A + (size_t)(m0 + ar) * lda + ac;
  const int sz  = swz(ar);                       // swz(ar+64) == swz(ar)
  const int ab0 = ar * 64 + (((tid & 3) ^ sz) << 4);
  const int ab1 = ab0 + 64 * 64;

  for (int s = 0; s < ksteps; ++s){
    const int kc = (s0 + s) * 32;
    // B tile: 8KB contiguous slab -> linear LDS (16B/lane x2)
    const char* bsrc = (const char*)Bt + ((size_t)(s0 + s) * ntot + n0) * 64;
    #pragma unroll
    for (int j = 0; j < 2; ++j){
      int off = w * 2048 + j * 1024;
      __builtin_amdgcn_global_load_lds(
        (const __attribute__((address_space(1))) void*)(bsrc + off + lane * 16),
        (__attribute__((address_space(3))) void*)((char*)smB + off),
        16, 0, 0);
    }
    // A tile: fp32 -> bf16 via native casts (cvt_pk), 16 elems/thread
    float4 a0 = *(const float4*)(ap + kc);
    float4 a1 = *(const float4*)(ap + kc + 4);
    float4 a2 = *(const float4*)(ap + (size_t)64 * lda + kc);
    float4 a3 = *(const float4*)(ap + (size_t)64 * lda + kc + 4);
    bf16x8 w0, w1;
    w0[0]=(__bf16)a0.x; w0[1]=(__bf16)a0.y; w0[2]=(__bf16)a0.z; w0[3]=(__bf16)a0.w;
    w0[4]=(__bf16)a1.x; w0[5]=(__bf16)a1.y; w0[6]=(__bf16)a1.z; w0[7]=(__bf16)a1.w;
    w1[0]=(__bf16)a2.x; w1[1]=(__bf16)a2.y; w1[2]=(__bf16)a2.z; w1[3]=(__bf16)a2.w;
    w1[4]=(__bf16)a3.x; w1[5]=(__bf16)a3.y; w1[6]=(__bf16)a3.z; w1[7]=(__bf16)a3.w;
    *(bf16x8*)((char*)smA + ab0) = w0;
    *(bf16x8*)((char*)smA + ab1) = w1;
    __syncthreads();

    bf16x8 af[4];
    #pragma unroll
    for (int m = 0; m < 4; ++m){
      int rl = wr * 64 + m * 16 + fr;
      af[m] = *(const bf16x8*)((const char*)smA + rl * 64 + ((g ^ swz(rl)) << 4));
    }
    #pragma unroll
    for (int n = 0; n < 4; ++n){
      int nl = wc * 64 + n * 16 + fr;
      bf16x8 bfv = *(const bf16x8*)((const char*)smB + nl * 64 + ((g ^ swz(nl)) << 4));
      #pragma unroll
      for (int m = 0; m < 4; ++m)
        acc[m][n] = __builtin_amdgcn_mfma_f32_16x16x32_bf16(af[m], bfv, acc[m][n], 0, 0, 0);
    }
    __syncthreads();
  }

  if (EPI == 0){
    #pragma unroll
    for (int n = 0; n < 4; ++n){
      int col = n0 + wc * 64 + n * 16 + fr;
      #pragma unroll
      for (int m = 0; m < 4; ++m){
        int row = m0 + wr * 64 + m * 16 + g * 4;
        #pragma unroll
        for (int j = 0; j < 4; ++j)
          outp[(size_t)(row + j) * ntot + col] = acc[m][n][j];
      }
    }
  } else {
    float p[16] = {};
    #pragma unroll
    for (int n = 0; n < 4; ++n){
      int col = wc * 64 + n * 16 + fr;
      float hpv = smHp[col], wsv = smWs[col];
      #pragma unroll
      for (int m = 0; m < 4; ++m)
        #pragma unroll
        for (int j = 0; j < 4; ++j)
          p[m * 4 + j] += tanh_fast(acc[m][n][j] + hpv) * wsv;
    }
    #pragma unroll
    for (int mask = 1; mask < 16; mask <<= 1)
      #pragma unroll
      for (int i = 0; i < 16; ++i)
        p[i] += __shfl_xor(p[i], mask);
    if (fr == 0){
      #pragma unroll
      for (int m = 0; m < 4; ++m)
        #pragma unroll
        for (int j = 0; j < 4; ++j)
          smRed[wc][wr * 64 + m * 16 + g * 4 + j] = p[m * 4 + j];
    }
    __syncthreads();
    if (tid < 128){
      int nb = n0 >> 7;
      epart[(size_t)nb * MTOT + m0 + tid] = smRed[0][tid] + smRed[1][tid];
    }
  }
}

// ---------------- fused softmax + context: x_full[:,0:512], alpha -> d_out ----------------
__global__ void ctx_softmax(const float* __restrict__ epart, const float* __restrict__ batch_H,
                            float* __restrict__ x_full, float* __restrict__ alpha_out){
  __shared__ float sa[256];
  __shared__ float red[4], red2[4];
  __shared__ f32x4 sred[8][32];
  int b = blockIdx.x, q = blockIdx.y, tid = threadIdx.x;

  float e = 0.f;
  #pragma unroll
  for (int p = 0; p < 4; ++p) e += epart[(size_t)p * MTOT + b * 256 + tid];
  float m = e;
  #pragma unroll
  for (int mask = 1; mask < 64; mask <<= 1) m = fmaxf(m, __shfl_xor(m, mask));
  int w = tid >> 6;
  if ((tid & 63) == 0) red[w] = m;
  __syncthreads();
  m = fmaxf(fmaxf(red[0], red[1]), fmaxf(red[2], red[3]));
  float ev = __expf(e - m);
  float s = ev;
  #pragma unroll
  for (int mask = 1; mask < 64; mask <<= 1) s += __shfl_xor(s, mask);
  if ((tid & 63) == 0) red2[w] = s;
  __syncthreads();
  s = red2[0] + red2[1] + red2[2] + red2[3];
  float a = ev / s;
  sa[tid] = a;
  if (q == 0) alpha_out[(size_t)b * 256 + tid] = a;
  __syncthreads();

  int c4 = tid & 31, tq = tid >> 5;
  const float4* bhp = (const float4*)(batch_H + (size_t)b * 131072) + (size_t)tq * 32 * 128 + q * 32 + c4;
  f32x4 acc = {0.f, 0.f, 0.f, 0.f};
  #pragma unroll 4
  for (int t = 0; t < 32; ++t){
    float av = sa[tq * 32 + t];
    float4 v = bhp[(size_t)t * 128];
    acc[0] += av * v.x; acc[1] += av * v.y; acc[2] += av * v.z; acc[3] += av * v.w;
  }
  sred[tq][c4] = acc;
  __syncthreads();
  if (tid < 32){
    f32x4 o = sred[0][tid];
    #pragma unroll
    for (int r = 1; r < 8; ++r){
      f32x4 v = sred[r][tid];
      o[0] += v[0]; o[1] += v[1]; o[2] += v[2]; o[3] += v[3];
    }
    float4 st; st.x = o[0]; st.y = o[1]; st.z = o[2]; st.w = o[3];
    *(float4*)(x_full + (size_t)b * KFULL + q * 128 + tid * 4) = st;
  }
}

// ---------------- LSTM gates: sum z parts + bias, apply gates ----------------
__global__ void gates_k(const float* __restrict__ zpart, const float* __restrict__ bias,
                        const float* __restrict__ prev_c, float* __restrict__ out){
  int idx = blockIdx.x * 256 + threadIdx.x;   // 512*512
  int b = idx >> 9, h = idx & 511;
  float zi = bias[h], zf = bias[512 + h], zg = bias[1024 + h], zo = bias[1536 + h];
  #pragma unroll
  for (int p = 0; p < 5; ++p){
    const float* zr = zpart + (size_t)p * 1048576 + (size_t)b * N4H;
    zi += zr[h]; zf += zr[512 + h]; zg += zr[1024 + h]; zo += zr[1536 + h];
  }
  float c = sigf(zf) * prev_c[idx] + sigf(zi) * tanh_fast(zg);
  float hn = sigf(zo) * tanh_fast(c);
  out[idx] = hn;               // h_new
  out[262144 + idx] = c;       // c_new
}

extern "C" void kernel_launch(void* const* d_in, const int* in_sizes, int n_in,
                              void* d_out, int out_size, void* d_ws, size_t ws_size,
                              hipStream_t stream){
  const float* prev_h  = (const float*)d_in[0];
  const float* prev_c  = (const float*)d_in[1];
  const float* batch_H = (const float*)d_in[2];
  const float* onehots = (const float*)d_in[3];
  const float* Wi      = (const float*)d_in[4];
  const float* Wh      = (const float*)d_in[5];
  const float* bh      = (const float*)d_in[6];
  const float* Ws      = (const float*)d_in[7];
  const float* Km      = (const float*)d_in[8];
  const float* R       = (const float*)d_in[9];
  const float* bb      = (const float*)d_in[10];
  float* out = (float*)d_out;

  char* ws = (char*)d_ws;
  u16*  wiT    = (u16*)(ws + 0);             // 512KB
  u16*  whT    = (u16*)(ws + 524288);        // 512KB
  u16*  wfT    = (u16*)(ws + 1048576);       // 4.375MB -> 5636096
  float* hpart = (float*)(ws + 5636096);     // 4MB -> 9830400
  float* epart = (float*)(ws + 9830400);     // 2MB -> 11927552
  float* x_full= (float*)(ws + 11927552);    // 2.1875MB -> 14221312
  float* zpart = (float*)(ws + 14221312);    // 20MB -> 35192832

  float* alpha = out + 524288;

  prep_w<<<11008, 256, 0, stream>>>(Wi, Wh, Km, R, wiT, whT, wfT);
  prep_x<<<1216, 256, 0, stream>>>(onehots, prev_h, x_full);
  gemm128<0><<<dim3(4, 4, 4), 256, 0, stream>>>(prev_h, 512, 4, whT, 512,
                                                hpart, 262144, nullptr, nullptr, nullptr, nullptr);
  gemm128<1><<<dim3(4096, 1, 1), 256, 0, stream>>>(batch_H, 512, 16, wiT, 512,
                                                   nullptr, 0, hpart, bh, Ws, epart);
  ctx_softmax<<<dim3(512, 4), 256, 0, stream>>>(epart, batch_H, x_full, alpha);
  gemm128<0><<<dim3(4, 16, 5), 256, 0, stream>>>(x_full, KFULL, 7, wfT, N4H,
                                                 zpart, 1048576, nullptr, nullptr, nullptr, nullptr);
  gates_k<<<1024, 256, 0, stream>>>(zpart, bb, prev_c, out);
}